// Round 4
// baseline (2737.504 us; speedup 1.0000x reference)
//
#include <hip/hip_runtime.h>
#include <cstdint>
#include <cstddef>

#define N_NODES  50000
#define N_EDGES  4000
#define NNZ_     400000
#define N_GRAPHS 64
#define C_DIM    1024
#define M_PAD    50048   // 391*128
#define BN_EPS   1e-5f

typedef float f32x4  __attribute__((ext_vector_type(4)));
typedef short bf16x8 __attribute__((ext_vector_type(8)));

__device__ __forceinline__ short f2bf(float f) {
  uint32_t u = __builtin_bit_cast(uint32_t, f);
  u += 0x7fffu + ((u >> 16) & 1u);          // RNE
  return (short)(u >> 16);
}

// ---------------- CSR build ----------------
__global__ void countDeg(const int* __restrict__ ni, const int* __restrict__ ei,
                         int* __restrict__ nd, int* __restrict__ ed) {
  int i = blockIdx.x * 256 + threadIdx.x;
  if (i < NNZ_) {
    atomicAdd(&nd[ni[i]], 1);
    atomicAdd(&ed[ei[i]], 1);
  }
}

__global__ void exscan(const int* __restrict__ deg, int* __restrict__ off, int n) {
  __shared__ int wsum[16];
  __shared__ int carry_s;
  int t = threadIdx.x, lane = t & 63, w = t >> 6;
  if (t == 0) carry_s = 0;
  __syncthreads();
  for (int base = 0; base < n; base += 1024) {
    int v = (base + t < n) ? deg[base + t] : 0;
    int x = v;
    #pragma unroll
    for (int d = 1; d < 64; d <<= 1) { int y = __shfl_up(x, d); if (lane >= d) x += y; }
    if (lane == 63) wsum[w] = x;
    __syncthreads();
    if (t < 16) {
      int y = wsum[t];
      #pragma unroll
      for (int d = 1; d < 16; d <<= 1) { int z = __shfl_up(y, d); if (t >= d) y += z; }
      wsum[t] = y;
    }
    __syncthreads();
    int c = carry_s;
    int incl = x + (w ? wsum[w - 1] : 0);
    if (base + t < n) off[base + t] = c + incl - v;
    int total = wsum[15];
    __syncthreads();
    if (t == 0) carry_s = c + total;
    __syncthreads();
  }
  if (threadIdx.x == 0) off[n] = carry_s;
}

__global__ void fillCSR(const int* __restrict__ ni, const int* __restrict__ ei,
                        const int* __restrict__ noff, const int* __restrict__ eoff,
                        int* __restrict__ ncur, int* __restrict__ ecur,
                        int* __restrict__ node_edge, int* __restrict__ edge_node) {
  int i = blockIdx.x * 256 + threadIdx.x;
  if (i < NNZ_) {
    int n = ni[i], e = ei[i];
    int pe = eoff[e] + atomicAdd(&ecur[e], 1);
    edge_node[pe] = n;
    int pn = noff[n] + atomicAdd(&ncur[n], 1);
    node_edge[pn] = e;
  }
}

__global__ void invdeg(const int* __restrict__ nd, const int* __restrict__ ed,
                       float* __restrict__ Dinv, float* __restrict__ Binv) {
  int i = blockIdx.x * 256 + threadIdx.x;
  if (i < N_NODES) { int d = nd[i]; Dinv[i] = d > 0 ? 1.f / (float)d : 0.f; }
  if (i < N_EDGES) { int d = ed[i]; Binv[i] = d > 0 ? 1.f / (float)d : 0.f; }
}

// ---------------- input transforms (fp32 -> bf16, pad, optional BN+ReLU) ----------------
__global__ void transformX(const float* __restrict__ X, short* __restrict__ Abf) {
  size_t idx = ((size_t)blockIdx.x * 256 + threadIdx.x) * 8;
  int row = (int)(idx >> 10);
  bf16x8 ov = {0, 0, 0, 0, 0, 0, 0, 0};
  if (row < N_NODES) {
    float v[8];
    *(f32x4*)&v[0] = *(const f32x4*)&X[idx];
    *(f32x4*)&v[4] = *(const f32x4*)&X[idx + 4];
    #pragma unroll
    for (int j = 0; j < 8; ++j) ov[j] = f2bf(v[j]);
  }
  *(bf16x8*)&Abf[idx] = ov;
}

__global__ void transformBN(const float* __restrict__ H, const float* __restrict__ sc,
                            const float* __restrict__ sh, short* __restrict__ Abf) {
  size_t idx = ((size_t)blockIdx.x * 256 + threadIdx.x) * 8;
  int row = (int)(idx >> 10);
  int c = (int)(idx & 1023);
  bf16x8 ov = {0, 0, 0, 0, 0, 0, 0, 0};
  if (row < N_NODES) {
    float v[8], s[8], h[8];
    *(f32x4*)&v[0] = *(const f32x4*)&H[idx];
    *(f32x4*)&v[4] = *(const f32x4*)&H[idx + 4];
    *(f32x4*)&s[0] = *(const f32x4*)&sc[c];
    *(f32x4*)&s[4] = *(const f32x4*)&sc[c + 4];
    *(f32x4*)&h[0] = *(const f32x4*)&sh[c];
    *(f32x4*)&h[4] = *(const f32x4*)&sh[c + 4];
    #pragma unroll
    for (int j = 0; j < 8; ++j) ov[j] = f2bf(fmaxf(v[j] * s[j] + h[j], 0.f));
  }
  *(bf16x8*)&Abf[idx] = ov;
}

// W [K][N] fp32 -> WT [N][K] bf16
__global__ void convertWT(const float* __restrict__ Wm, short* __restrict__ WT) {
  __shared__ float tile[64][65];
  int tx = threadIdx.x & 63, ty = threadIdx.x >> 6;  // ty 0..3
  int kb = blockIdx.x * 64, nb = blockIdx.y * 64;
  #pragma unroll
  for (int j = 0; j < 64; j += 4)
    tile[j + ty][tx] = Wm[(size_t)(kb + j + ty) * C_DIM + nb + tx];
  __syncthreads();
  #pragma unroll
  for (int j = 0; j < 64; j += 4)
    WT[(size_t)(nb + j + ty) * C_DIM + kb + tx] = f2bf(tile[tx][j + ty]);
}

// ---------------- GEMM: C[M,1024] = A[M,1024]bf16 x B (BT[1024,1024] bf16 row-major = W^T) ----------------
__global__ __launch_bounds__(256) void gemm_bf16(const short* __restrict__ A,
                                                 const short* __restrict__ BT,
                                                 float* __restrict__ Cc) {
  __shared__ __align__(16) short As[2][128 * 32];
  __shared__ __align__(16) short Bs[2][128 * 32];
  const int tid = threadIdx.x;
  const int w = tid >> 6;
  const int lane = tid & 63;
  const int bm = blockIdx.x, bn = blockIdx.y;
  const int wr = w >> 1, wc = w & 1;
  const int fr = lane & 15, kg = lane >> 4;
  const int qa = w * 2;
  const int srow = lane >> 2;        // 0..15
  const int skof = (lane & 3) * 8;   // 0,8,16,24

  f32x4 acc[4][4] = {};

  auto stage = [&](int ks, int buf) {
    #pragma unroll
    for (int c2 = 0; c2 < 2; ++c2) {
      int q = qa + c2;
      int row = q * 16 + srow;
      size_t gA = (size_t)(bm * 128 + row) * C_DIM + ks * 32 + skof;
      size_t gB = (size_t)(bn * 128 + row) * C_DIM + ks * 32 + skof;
      __builtin_amdgcn_global_load_lds(
          (__attribute__((address_space(1))) void*)(A + gA),
          (__attribute__((address_space(3))) void*)(&As[buf][q * 512]), 16, 0, 0);
      __builtin_amdgcn_global_load_lds(
          (__attribute__((address_space(1))) void*)(BT + gB),
          (__attribute__((address_space(3))) void*)(&Bs[buf][q * 512]), 16, 0, 0);
    }
  };
  auto compute = [&](int buf) {
    bf16x8 a[4], b[4];
    #pragma unroll
    for (int m = 0; m < 4; ++m)
      a[m] = *(const bf16x8*)&As[buf][(wr * 64 + m * 16 + fr) * 32 + kg * 8];
    #pragma unroll
    for (int n = 0; n < 4; ++n)
      b[n] = *(const bf16x8*)&Bs[buf][(wc * 64 + n * 16 + fr) * 32 + kg * 8];
    #pragma unroll
    for (int m = 0; m < 4; ++m)
      #pragma unroll
      for (int n = 0; n < 4; ++n)
        acc[m][n] = __builtin_amdgcn_mfma_f32_16x16x32_bf16(a[m], b[n], acc[m][n], 0, 0, 0);
  };

  stage(0, 0);
  __syncthreads();
  for (int ks = 0; ks < 31; ++ks) {
    stage(ks + 1, (ks + 1) & 1);
    compute(ks & 1);
    __syncthreads();
  }
  compute(1);

  const int row0 = bm * 128 + wr * 64 + kg * 4;
  const int col0 = bn * 128 + wc * 64 + fr;
  #pragma unroll
  for (int m = 0; m < 4; ++m) {
    #pragma unroll
    for (int n = 0; n < 4; ++n) {
      int r = row0 + m * 16, cc = col0 + n * 16;
      #pragma unroll
      for (int j = 0; j < 4; ++j)
        Cc[(size_t)(r + j) * C_DIM + cc] = acc[m][n][j];
    }
  }
}

// ---------------- hypergraph aggregation ----------------
__global__ void phaseA(const float* __restrict__ H, const int* __restrict__ eoff,
                       const int* __restrict__ enode, const float* __restrict__ Binv,
                       float* __restrict__ M) {
  int e = blockIdx.x;
  int t = threadIdx.x;
  int beg = eoff[e], end = eoff[e + 1];
  f32x4 acc0 = {0.f, 0.f, 0.f, 0.f}, acc1 = {0.f, 0.f, 0.f, 0.f};
  int i = beg;
  for (; i + 1 < end; i += 2) {
    int n0 = enode[i], n1 = enode[i + 1];
    acc0 += *(const f32x4*)&H[(size_t)n0 * C_DIM + t * 4];
    acc1 += *(const f32x4*)&H[(size_t)n1 * C_DIM + t * 4];
  }
  if (i < end) acc0 += *(const f32x4*)&H[(size_t)enode[i] * C_DIM + t * 4];
  float bi = Binv[e];
  *(f32x4*)&M[(size_t)e * C_DIM + t * 4] = (acc0 + acc1) * bi;
}

__global__ void phaseB(const float* __restrict__ M, const int* __restrict__ noff,
                       const int* __restrict__ nedge, const float* __restrict__ Dinv,
                       const float* __restrict__ bias, float* __restrict__ Out) {
  int n = blockIdx.x;
  int t = threadIdx.x;
  int beg = noff[n], end = noff[n + 1];
  f32x4 acc0 = {0.f, 0.f, 0.f, 0.f}, acc1 = {0.f, 0.f, 0.f, 0.f};
  int i = beg;
  for (; i + 1 < end; i += 2) {
    int e0 = nedge[i], e1 = nedge[i + 1];
    acc0 += *(const f32x4*)&M[(size_t)e0 * C_DIM + t * 4];
    acc1 += *(const f32x4*)&M[(size_t)e1 * C_DIM + t * 4];
  }
  if (i < end) acc0 += *(const f32x4*)&M[(size_t)nedge[i] * C_DIM + t * 4];
  float di = Dinv[n];
  f32x4 b = *(const f32x4*)&bias[t * 4];
  *(f32x4*)&Out[(size_t)n * C_DIM + t * 4] = (acc0 + acc1) * di + b;
}

// ---------------- batch norm ----------------
__global__ void bnstats(const float* __restrict__ H, float* __restrict__ cs,
                        float* __restrict__ cq) {
  int c = threadIdx.x * 4;
  int r0 = blockIdx.x * 128;
  int r1 = r0 + 128 < N_NODES ? r0 + 128 : N_NODES;
  float s[4] = {0, 0, 0, 0}, q[4] = {0, 0, 0, 0};
  for (int r = r0; r < r1; ++r) {
    f32x4 v = *(const f32x4*)&H[(size_t)r * C_DIM + c];
    #pragma unroll
    for (int j = 0; j < 4; ++j) { s[j] += v[j]; q[j] += v[j] * v[j]; }
  }
  #pragma unroll
  for (int j = 0; j < 4; ++j) {
    atomicAdd(&cs[c + j], s[j]);
    atomicAdd(&cq[c + j], q[j]);
  }
}

__global__ void bnfinal(const float* __restrict__ cs, const float* __restrict__ cq,
                        const float* __restrict__ g, const float* __restrict__ be,
                        float* __restrict__ scale, float* __restrict__ shift) {
  int c = blockIdx.x * 256 + threadIdx.x;
  const float invN = 1.f / (float)N_NODES;
  float mu = cs[c] * invN;
  float var = cq[c] * invN - mu * mu;
  float rs = rsqrtf(var + BN_EPS);
  float scl = g[c] * rs;
  scale[c] = scl;
  shift[c] = be[c] - mu * scl;
}

// ---------------- final pooling + fc + sigmoid ----------------
__global__ void finaldot(const float* __restrict__ H, const float* __restrict__ sc,
                         const float* __restrict__ sh, const float* __restrict__ Wfc,
                         const int* __restrict__ batch, float* __restrict__ gsum,
                         int* __restrict__ gcnt) {
  int row = blockIdx.x * 4 + (threadIdx.x >> 6);
  int lane = threadIdx.x & 63;
  if (row >= N_NODES) return;
  const float* hr = H + (size_t)row * C_DIM;
  float s = 0.f;
  #pragma unroll
  for (int j = 0; j < 4; ++j) {
    int c = j * 256 + lane * 4;
    f32x4 v = *(const f32x4*)&hr[c];
    f32x4 a = *(const f32x4*)&sc[c];
    f32x4 b = *(const f32x4*)&sh[c];
    f32x4 w = *(const f32x4*)&Wfc[c];
    #pragma unroll
    for (int k = 0; k < 4; ++k) s += fmaxf(v[k] * a[k] + b[k], 0.f) * w[k];
  }
  #pragma unroll
  for (int off = 32; off; off >>= 1) s += __shfl_down(s, off);
  if (lane == 0) {
    int g = batch[row];
    atomicAdd(&gsum[g], s);
    atomicAdd(&gcnt[g], 1);
  }
}

__global__ void finalout(const float* __restrict__ gsum, const int* __restrict__ gcnt,
                         const float* __restrict__ bfc, float* __restrict__ out) {
  int g = threadIdx.x;
  float cnt = (float)(gcnt[g] > 0 ? gcnt[g] : 1);
  float v = gsum[g] / cnt + bfc[0];
  out[g] = 1.f / (1.f + expf(-v));
}

// ---------------- host launcher ----------------
extern "C" void kernel_launch(void* const* d_in, const int* in_sizes, int n_in,
                              void* d_out, int out_size, void* d_ws, size_t ws_size,
                              hipStream_t stream) {
  const float* x        = (const float*)d_in[0];
  const int*   node_idx = (const int*)d_in[1];
  const int*   hedge_idx= (const int*)d_in[2];
  const int*   batch    = (const int*)d_in[3];
  const float* W[3]  = {(const float*)d_in[4], (const float*)d_in[6], (const float*)d_in[8]};
  const float* bb[3] = {(const float*)d_in[5], (const float*)d_in[7], (const float*)d_in[9]};
  const float* g[3]  = {(const float*)d_in[10], (const float*)d_in[12], (const float*)d_in[14]};
  const float* be[3] = {(const float*)d_in[11], (const float*)d_in[13], (const float*)d_in[15]};
  const float* Wfc   = (const float*)d_in[16];
  const float* bfc   = (const float*)d_in[17];
  float* out = (float*)d_out;

  char* ws = (char*)d_ws;
  size_t o = 0;
  auto take = [&](size_t bytes) -> char* {
    char* p = ws + o;
    o += (bytes + 255) & ~(size_t)255;
    return p;
  };
  short* Abf  = (short*)take((size_t)M_PAD * C_DIM * 2);
  short* WT   = (short*)take((size_t)C_DIM * C_DIM * 2);
  float* Hbuf = (float*)take((size_t)M_PAD * C_DIM * 4);
  float* Mbuf = (float*)take((size_t)N_EDGES * C_DIM * 4);
  char*  zgrp = take(432512);
  int*   node_deg = (int*)zgrp;
  int*   edge_deg = (int*)(zgrp + 200000);
  int*   node_cur = (int*)(zgrp + 216000);
  int*   edge_cur = (int*)(zgrp + 416000);
  float* gsum     = (float*)(zgrp + 432000);
  int*   gcnt     = (int*)(zgrp + 432256);
  int* node_off  = (int*)take((N_NODES + 1) * 4);
  int* edge_off  = (int*)take((N_EDGES + 1) * 4);
  int* node_edge = (int*)take((size_t)NNZ_ * 4);
  int* edge_node = (int*)take((size_t)NNZ_ * 4);
  float* Dinv = (float*)take(N_NODES * 4);
  float* Binv = (float*)take(N_EDGES * 4);
  float* colstats = (float*)take(8192);   // colsum[1024] + colsq[1024]
  float* colsum = colstats;
  float* colsq  = colstats + 1024;
  float* scale = (float*)take(4096);
  float* shift = (float*)take(4096);

  // zero accumulators (must be re-zeroed every call)
  hipMemsetAsync(zgrp, 0, 432512, stream);

  // degree + CSR build
  countDeg<<<(NNZ_ + 255) / 256, 256, 0, stream>>>(node_idx, hedge_idx, node_deg, edge_deg);
  exscan<<<1, 1024, 0, stream>>>(edge_deg, edge_off, N_EDGES);
  exscan<<<1, 1024, 0, stream>>>(node_deg, node_off, N_NODES);
  fillCSR<<<(NNZ_ + 255) / 256, 256, 0, stream>>>(node_idx, hedge_idx, node_off, edge_off,
                                                  node_cur, edge_cur, node_edge, edge_node);
  invdeg<<<(N_NODES + 255) / 256, 256, 0, stream>>>(node_deg, edge_deg, Dinv, Binv);

  const int tgrid = (int)((size_t)M_PAD * C_DIM / (8 * 256));  // 25024
  for (int L = 0; L < 3; ++L) {
    if (L == 0)
      transformX<<<tgrid, 256, 0, stream>>>(x, Abf);
    else
      transformBN<<<tgrid, 256, 0, stream>>>(Hbuf, scale, shift, Abf);
    convertWT<<<dim3(16, 16), 256, 0, stream>>>(W[L], WT);
    gemm_bf16<<<dim3(M_PAD / 128, C_DIM / 128), 256, 0, stream>>>(Abf, WT, Hbuf);
    phaseA<<<N_EDGES, 256, 0, stream>>>(Hbuf, edge_off, edge_node, Binv, Mbuf);
    phaseB<<<N_NODES, 256, 0, stream>>>(Mbuf, node_off, node_edge, Dinv, bb[L], Hbuf);
    hipMemsetAsync(colstats, 0, 8192, stream);
    bnstats<<<391, 256, 0, stream>>>(Hbuf, colsum, colsq);
    bnfinal<<<4, 256, 0, stream>>>(colsum, colsq, g[L], be[L], scale, shift);
  }
  finaldot<<<(N_NODES + 3) / 4, 256, 0, stream>>>(Hbuf, scale, shift, Wfc, batch, gsum, gcnt);
  finalout<<<1, 64, 0, stream>>>(gsum, gcnt, bfc, out);
}

// Round 5
// 2450.996 us; speedup vs baseline: 1.1169x; 1.1169x over previous
//
#include <hip/hip_runtime.h>
#include <cstdint>
#include <cstddef>

#define N_NODES  50000
#define N_EDGES  4000
#define NNZ_     400000
#define N_GRAPHS 64
#define C_DIM    1024
#define M_PAD    50048   // 391*128
#define NBLK_BN  391
#define BN_EPS   1e-5f

typedef float f32x4  __attribute__((ext_vector_type(4)));
typedef short bf16x8 __attribute__((ext_vector_type(8)));

__device__ __forceinline__ short f2bf(float f) {
  uint32_t u = __builtin_bit_cast(uint32_t, f);
  u += 0x7fffu + ((u >> 16) & 1u);          // RNE
  return (short)(u >> 16);
}

// ---------------- CSR build ----------------
__global__ void countDeg(const int* __restrict__ ni, const int* __restrict__ ei,
                         int* __restrict__ nd, int* __restrict__ ed) {
  int i = blockIdx.x * 256 + threadIdx.x;
  if (i < NNZ_) {
    atomicAdd(&nd[ni[i]], 1);
    atomicAdd(&ed[ei[i]], 1);
  }
}

__global__ void exscan(const int* __restrict__ deg, int* __restrict__ off, int n) {
  __shared__ int wsum[16];
  __shared__ int carry_s;
  int t = threadIdx.x, lane = t & 63, w = t >> 6;
  if (t == 0) carry_s = 0;
  __syncthreads();
  for (int base = 0; base < n; base += 1024) {
    int v = (base + t < n) ? deg[base + t] : 0;
    int x = v;
    #pragma unroll
    for (int d = 1; d < 64; d <<= 1) { int y = __shfl_up(x, d); if (lane >= d) x += y; }
    if (lane == 63) wsum[w] = x;
    __syncthreads();
    if (t < 16) {
      int y = wsum[t];
      #pragma unroll
      for (int d = 1; d < 16; d <<= 1) { int z = __shfl_up(y, d); if (t >= d) y += z; }
      wsum[t] = y;
    }
    __syncthreads();
    int c = carry_s;
    int incl = x + (w ? wsum[w - 1] : 0);
    if (base + t < n) off[base + t] = c + incl - v;
    int total = wsum[15];
    __syncthreads();
    if (t == 0) carry_s = c + total;
    __syncthreads();
  }
  if (threadIdx.x == 0) off[n] = carry_s;
}

__global__ void fillCSR(const int* __restrict__ ni, const int* __restrict__ ei,
                        const int* __restrict__ noff, const int* __restrict__ eoff,
                        int* __restrict__ ncur, int* __restrict__ ecur,
                        int* __restrict__ node_edge, int* __restrict__ edge_node) {
  int i = blockIdx.x * 256 + threadIdx.x;
  if (i < NNZ_) {
    int n = ni[i], e = ei[i];
    int pe = eoff[e] + atomicAdd(&ecur[e], 1);
    edge_node[pe] = n;
    int pn = noff[n] + atomicAdd(&ncur[n], 1);
    node_edge[pn] = e;
  }
}

__global__ void invdeg(const int* __restrict__ nd, const int* __restrict__ ed,
                       float* __restrict__ Dinv, float* __restrict__ Binv) {
  int i = blockIdx.x * 256 + threadIdx.x;
  if (i < N_NODES) { int d = nd[i]; Dinv[i] = d > 0 ? 1.f / (float)d : 0.f; }
  if (i < N_EDGES) { int d = ed[i]; Binv[i] = d > 0 ? 1.f / (float)d : 0.f; }
}

// ---------------- input transforms (fp32 -> bf16, pad, optional BN+ReLU) ----------------
__global__ void transformX(const float* __restrict__ X, short* __restrict__ Abf) {
  size_t idx = ((size_t)blockIdx.x * 256 + threadIdx.x) * 8;
  int row = (int)(idx >> 10);
  bf16x8 ov = {0, 0, 0, 0, 0, 0, 0, 0};
  if (row < N_NODES) {
    float v[8];
    *(f32x4*)&v[0] = *(const f32x4*)&X[idx];
    *(f32x4*)&v[4] = *(const f32x4*)&X[idx + 4];
    #pragma unroll
    for (int j = 0; j < 8; ++j) ov[j] = f2bf(v[j]);
  }
  *(bf16x8*)&Abf[idx] = ov;
}

__global__ void transformBN(const float* __restrict__ H, const float* __restrict__ sc,
                            const float* __restrict__ sh, short* __restrict__ Abf) {
  size_t idx = ((size_t)blockIdx.x * 256 + threadIdx.x) * 8;
  int row = (int)(idx >> 10);
  int c = (int)(idx & 1023);
  bf16x8 ov = {0, 0, 0, 0, 0, 0, 0, 0};
  if (row < N_NODES) {
    float v[8], s[8], h[8];
    *(f32x4*)&v[0] = *(const f32x4*)&H[idx];
    *(f32x4*)&v[4] = *(const f32x4*)&H[idx + 4];
    *(f32x4*)&s[0] = *(const f32x4*)&sc[c];
    *(f32x4*)&s[4] = *(const f32x4*)&sc[c + 4];
    *(f32x4*)&h[0] = *(const f32x4*)&sh[c];
    *(f32x4*)&h[4] = *(const f32x4*)&sh[c + 4];
    #pragma unroll
    for (int j = 0; j < 8; ++j) ov[j] = f2bf(fmaxf(v[j] * s[j] + h[j], 0.f));
  }
  *(bf16x8*)&Abf[idx] = ov;
}

// W [K][N] fp32 -> WT [N][K] bf16
__global__ void convertWT(const float* __restrict__ Wm, short* __restrict__ WT) {
  __shared__ float tile[64][65];
  int tx = threadIdx.x & 63, ty = threadIdx.x >> 6;  // ty 0..3
  int kb = blockIdx.x * 64, nb = blockIdx.y * 64;
  #pragma unroll
  for (int j = 0; j < 64; j += 4)
    tile[j + ty][tx] = Wm[(size_t)(kb + j + ty) * C_DIM + nb + tx];
  __syncthreads();
  #pragma unroll
  for (int j = 0; j < 64; j += 4)
    WT[(size_t)(nb + j + ty) * C_DIM + kb + tx] = f2bf(tile[tx][j + ty]);
}

// ---------------- GEMM: C[M,1024] = A[M,1024]bf16 x B (BT[1024,1024] bf16 row-major = W^T) ----------------
__global__ __launch_bounds__(256) void gemm_bf16(const short* __restrict__ A,
                                                 const short* __restrict__ BT,
                                                 float* __restrict__ Cc) {
  __shared__ __align__(16) short As[2][128 * 32];
  __shared__ __align__(16) short Bs[2][128 * 32];
  const int tid = threadIdx.x;
  const int w = tid >> 6;
  const int lane = tid & 63;
  const int bm = blockIdx.x, bn = blockIdx.y;
  const int wr = w >> 1, wc = w & 1;
  const int fr = lane & 15, kg = lane >> 4;
  const int qa = w * 2;
  const int srow = lane >> 2;        // 0..15
  const int skof = (lane & 3) * 8;   // 0,8,16,24

  f32x4 acc[4][4] = {};

  auto stage = [&](int ks, int buf) {
    #pragma unroll
    for (int c2 = 0; c2 < 2; ++c2) {
      int q = qa + c2;
      int row = q * 16 + srow;
      size_t gA = (size_t)(bm * 128 + row) * C_DIM + ks * 32 + skof;
      size_t gB = (size_t)(bn * 128 + row) * C_DIM + ks * 32 + skof;
      __builtin_amdgcn_global_load_lds(
          (__attribute__((address_space(1))) void*)(A + gA),
          (__attribute__((address_space(3))) void*)(&As[buf][q * 512]), 16, 0, 0);
      __builtin_amdgcn_global_load_lds(
          (__attribute__((address_space(1))) void*)(BT + gB),
          (__attribute__((address_space(3))) void*)(&Bs[buf][q * 512]), 16, 0, 0);
    }
  };
  auto compute = [&](int buf) {
    bf16x8 a[4], b[4];
    #pragma unroll
    for (int m = 0; m < 4; ++m)
      a[m] = *(const bf16x8*)&As[buf][(wr * 64 + m * 16 + fr) * 32 + kg * 8];
    #pragma unroll
    for (int n = 0; n < 4; ++n)
      b[n] = *(const bf16x8*)&Bs[buf][(wc * 64 + n * 16 + fr) * 32 + kg * 8];
    #pragma unroll
    for (int m = 0; m < 4; ++m)
      #pragma unroll
      for (int n = 0; n < 4; ++n)
        acc[m][n] = __builtin_amdgcn_mfma_f32_16x16x32_bf16(a[m], b[n], acc[m][n], 0, 0, 0);
  };

  stage(0, 0);
  __syncthreads();
  for (int ks = 0; ks < 31; ++ks) {
    stage(ks + 1, (ks + 1) & 1);
    compute(ks & 1);
    __syncthreads();
  }
  compute(1);

  const int row0 = bm * 128 + wr * 64 + kg * 4;
  const int col0 = bn * 128 + wc * 64 + fr;
  #pragma unroll
  for (int m = 0; m < 4; ++m) {
    #pragma unroll
    for (int n = 0; n < 4; ++n) {
      int r = row0 + m * 16, cc = col0 + n * 16;
      #pragma unroll
      for (int j = 0; j < 4; ++j)
        Cc[(size_t)(r + j) * C_DIM + cc] = acc[m][n][j];
    }
  }
}

// ---------------- hypergraph aggregation ----------------
__global__ void phaseA(const float* __restrict__ H, const int* __restrict__ eoff,
                       const int* __restrict__ enode, const float* __restrict__ Binv,
                       float* __restrict__ M) {
  int e = blockIdx.x;
  int t = threadIdx.x;
  int beg = eoff[e], end = eoff[e + 1];
  f32x4 acc0 = {0.f, 0.f, 0.f, 0.f}, acc1 = {0.f, 0.f, 0.f, 0.f};
  int i = beg;
  for (; i + 1 < end; i += 2) {
    int n0 = enode[i], n1 = enode[i + 1];
    acc0 += *(const f32x4*)&H[(size_t)n0 * C_DIM + t * 4];
    acc1 += *(const f32x4*)&H[(size_t)n1 * C_DIM + t * 4];
  }
  if (i < end) acc0 += *(const f32x4*)&H[(size_t)enode[i] * C_DIM + t * 4];
  float bi = Binv[e];
  *(f32x4*)&M[(size_t)e * C_DIM + t * 4] = (acc0 + acc1) * bi;
}

__global__ void phaseB(const float* __restrict__ M, const int* __restrict__ noff,
                       const int* __restrict__ nedge, const float* __restrict__ Dinv,
                       const float* __restrict__ bias, float* __restrict__ Out) {
  int n = blockIdx.x;
  int t = threadIdx.x;
  int beg = noff[n], end = noff[n + 1];
  f32x4 acc0 = {0.f, 0.f, 0.f, 0.f}, acc1 = {0.f, 0.f, 0.f, 0.f};
  int i = beg;
  for (; i + 1 < end; i += 2) {
    int e0 = nedge[i], e1 = nedge[i + 1];
    acc0 += *(const f32x4*)&M[(size_t)e0 * C_DIM + t * 4];
    acc1 += *(const f32x4*)&M[(size_t)e1 * C_DIM + t * 4];
  }
  if (i < end) acc0 += *(const f32x4*)&M[(size_t)nedge[i] * C_DIM + t * 4];
  float di = Dinv[n];
  f32x4 b = *(const f32x4*)&bias[t * 4];
  *(f32x4*)&Out[(size_t)n * C_DIM + t * 4] = (acc0 + acc1) * di + b;
}

// ---------------- batch norm: atomic-free two-stage ----------------
__global__ void bnstats_part(const float* __restrict__ H, float* __restrict__ ps,
                             float* __restrict__ pq) {
  int c = threadIdx.x * 4;
  int b = blockIdx.x;
  int r0 = b * 128;
  int r1 = r0 + 128 < N_NODES ? r0 + 128 : N_NODES;
  f32x4 s = {0.f, 0.f, 0.f, 0.f}, q = {0.f, 0.f, 0.f, 0.f};
  for (int r = r0; r < r1; ++r) {
    f32x4 v = *(const f32x4*)&H[(size_t)r * C_DIM + c];
    s += v;
    q += v * v;
  }
  *(f32x4*)&ps[(size_t)b * C_DIM + c] = s;
  *(f32x4*)&pq[(size_t)b * C_DIM + c] = q;
}

__global__ void bnfinal2(const float* __restrict__ ps, const float* __restrict__ pq,
                         const float* __restrict__ g, const float* __restrict__ be,
                         float* __restrict__ scale, float* __restrict__ shift) {
  int c = blockIdx.x * 256 + threadIdx.x;
  float s = 0.f, q = 0.f;
  for (int p = 0; p < NBLK_BN; ++p) {
    s += ps[(size_t)p * C_DIM + c];
    q += pq[(size_t)p * C_DIM + c];
  }
  const float invN = 1.f / (float)N_NODES;
  float mu = s * invN;
  float var = q * invN - mu * mu;
  float rs = rsqrtf(var + BN_EPS);
  float scl = g[c] * rs;
  scale[c] = scl;
  shift[c] = be[c] - mu * scl;
}

// ---------------- final pooling + fc + sigmoid (atomic-light) ----------------
__global__ void finaldot_rows(const float* __restrict__ H, const float* __restrict__ sc,
                              const float* __restrict__ sh, const float* __restrict__ Wfc,
                              float* __restrict__ rows) {
  int row = blockIdx.x * 4 + (threadIdx.x >> 6);
  int lane = threadIdx.x & 63;
  if (row >= N_NODES) return;
  const float* hr = H + (size_t)row * C_DIM;
  float s = 0.f;
  #pragma unroll
  for (int j = 0; j < 4; ++j) {
    int c = j * 256 + lane * 4;
    f32x4 v = *(const f32x4*)&hr[c];
    f32x4 a = *(const f32x4*)&sc[c];
    f32x4 b = *(const f32x4*)&sh[c];
    f32x4 w = *(const f32x4*)&Wfc[c];
    #pragma unroll
    for (int k = 0; k < 4; ++k) s += fmaxf(v[k] * a[k] + b[k], 0.f) * w[k];
  }
  #pragma unroll
  for (int off = 32; off; off >>= 1) s += __shfl_down(s, off);
  if (lane == 0) rows[row] = s;
}

// batch is sorted -> each 1024-row block spans ~2 graphs; LDS bins then few global atomics
__global__ void poolbin(const float* __restrict__ rows, const int* __restrict__ batch,
                        float* __restrict__ gsum, int* __restrict__ gcnt) {
  __shared__ float bins[N_GRAPHS];
  __shared__ int cbin[N_GRAPHS];
  int t = threadIdx.x;
  if (t < N_GRAPHS) { bins[t] = 0.f; cbin[t] = 0; }
  __syncthreads();
  int quad = blockIdx.x * 256 + t;            // 12500 quads = 50000 rows
  if (quad * 4 < N_NODES) {
    f32x4 r = *(const f32x4*)&rows[quad * 4];
    int4 bi = *(const int4*)&batch[quad * 4];
    int g0 = bi.x;
    float acc = r[0];
    int cc = 1;
    int gn[3] = {bi.y, bi.z, bi.w};
    float rn[3] = {r[1], r[2], r[3]};
    #pragma unroll
    for (int j = 0; j < 3; ++j) {
      if (gn[j] == g0) { acc += rn[j]; ++cc; }
      else {
        atomicAdd(&bins[g0], acc);
        atomicAdd(&cbin[g0], cc);
        g0 = gn[j]; acc = rn[j]; cc = 1;
      }
    }
    atomicAdd(&bins[g0], acc);
    atomicAdd(&cbin[g0], cc);
  }
  __syncthreads();
  if (t < N_GRAPHS && cbin[t] > 0) {
    atomicAdd(&gsum[t], bins[t]);
    atomicAdd(&gcnt[t], cbin[t]);
  }
}

__global__ void finalout(const float* __restrict__ gsum, const int* __restrict__ gcnt,
                         const float* __restrict__ bfc, float* __restrict__ out) {
  int g = threadIdx.x;
  float cnt = (float)(gcnt[g] > 0 ? gcnt[g] : 1);
  float v = gsum[g] / cnt + bfc[0];
  out[g] = 1.f / (1.f + expf(-v));
}

// ---------------- host launcher ----------------
extern "C" void kernel_launch(void* const* d_in, const int* in_sizes, int n_in,
                              void* d_out, int out_size, void* d_ws, size_t ws_size,
                              hipStream_t stream) {
  const float* x        = (const float*)d_in[0];
  const int*   node_idx = (const int*)d_in[1];
  const int*   hedge_idx= (const int*)d_in[2];
  const int*   batch    = (const int*)d_in[3];
  const float* W[3]  = {(const float*)d_in[4], (const float*)d_in[6], (const float*)d_in[8]};
  const float* bb[3] = {(const float*)d_in[5], (const float*)d_in[7], (const float*)d_in[9]};
  const float* g[3]  = {(const float*)d_in[10], (const float*)d_in[12], (const float*)d_in[14]};
  const float* be[3] = {(const float*)d_in[11], (const float*)d_in[13], (const float*)d_in[15]};
  const float* Wfc   = (const float*)d_in[16];
  const float* bfc   = (const float*)d_in[17];
  float* out = (float*)d_out;

  char* ws = (char*)d_ws;
  size_t o = 0;
  auto take = [&](size_t bytes) -> char* {
    char* p = ws + o;
    o += (bytes + 255) & ~(size_t)255;
    return p;
  };
  short* Abf  = (short*)take((size_t)M_PAD * C_DIM * 2);
  short* WT   = (short*)take((size_t)C_DIM * C_DIM * 2);
  float* Hbuf = (float*)take((size_t)M_PAD * C_DIM * 4);
  float* Mbuf = (float*)take((size_t)N_EDGES * C_DIM * 4);
  char*  zgrp = take(432512);
  int*   node_deg = (int*)zgrp;
  int*   edge_deg = (int*)(zgrp + 200000);
  int*   node_cur = (int*)(zgrp + 216000);
  int*   edge_cur = (int*)(zgrp + 416000);
  float* gsum     = (float*)(zgrp + 432000);
  int*   gcnt     = (int*)(zgrp + 432256);
  int* node_off  = (int*)take((N_NODES + 1) * 4);
  int* edge_off  = (int*)take((N_EDGES + 1) * 4);
  int* node_edge = (int*)take((size_t)NNZ_ * 4);
  int* edge_node = (int*)take((size_t)NNZ_ * 4);
  float* Dinv = (float*)take(N_NODES * 4);
  float* Binv = (float*)take(N_EDGES * 4);
  float* scale = (float*)take(4096);
  float* shift = (float*)take(4096);
  float* part_s = (float*)take((size_t)NBLK_BN * C_DIM * 4);
  float* part_q = (float*)take((size_t)NBLK_BN * C_DIM * 4);
  float* rows   = (float*)take((size_t)N_NODES * 4);

  // zero atomic accumulators (must be re-zeroed every call)
  hipMemsetAsync(zgrp, 0, 432512, stream);

  // degree + CSR build
  countDeg<<<(NNZ_ + 255) / 256, 256, 0, stream>>>(node_idx, hedge_idx, node_deg, edge_deg);
  exscan<<<1, 1024, 0, stream>>>(edge_deg, edge_off, N_EDGES);
  exscan<<<1, 1024, 0, stream>>>(node_deg, node_off, N_NODES);
  fillCSR<<<(NNZ_ + 255) / 256, 256, 0, stream>>>(node_idx, hedge_idx, node_off, edge_off,
                                                  node_cur, edge_cur, node_edge, edge_node);
  invdeg<<<(N_NODES + 255) / 256, 256, 0, stream>>>(node_deg, edge_deg, Dinv, Binv);

  const int tgrid = (int)((size_t)M_PAD * C_DIM / (8 * 256));  // 25024
  for (int L = 0; L < 3; ++L) {
    if (L == 0)
      transformX<<<tgrid, 256, 0, stream>>>(x, Abf);
    else
      transformBN<<<tgrid, 256, 0, stream>>>(Hbuf, scale, shift, Abf);
    convertWT<<<dim3(16, 16), 256, 0, stream>>>(W[L], WT);
    gemm_bf16<<<dim3(M_PAD / 128, C_DIM / 128), 256, 0, stream>>>(Abf, WT, Hbuf);
    phaseA<<<N_EDGES, 256, 0, stream>>>(Hbuf, edge_off, edge_node, Binv, Mbuf);
    phaseB<<<N_NODES, 256, 0, stream>>>(Mbuf, node_off, node_edge, Dinv, bb[L], Hbuf);
    bnstats_part<<<NBLK_BN, 256, 0, stream>>>(Hbuf, part_s, part_q);
    bnfinal2<<<4, 256, 0, stream>>>(part_s, part_q, g[L], be[L], scale, shift);
  }
  finaldot_rows<<<(N_NODES + 3) / 4, 256, 0, stream>>>(Hbuf, scale, shift, Wfc, rows);
  poolbin<<<(N_NODES / 4 + 255) / 256, 256, 0, stream>>>(rows, batch, gsum, gcnt);
  finalout<<<1, 64, 0, stream>>>(gsum, gcnt, bfc, out);
}

// Round 6
// 1854.278 us; speedup vs baseline: 1.4763x; 1.3218x over previous
//
#include <hip/hip_runtime.h>
#include <cstdint>
#include <cstddef>

#define N_NODES  50000
#define N_EDGES  4000
#define E_PAD    4096    // 32*128
#define NNZ_     400000
#define N_GRAPHS 64
#define C_DIM    1024
#define NBLK_BN  391
#define BN_EPS   1e-5f

typedef float f32x4  __attribute__((ext_vector_type(4)));
typedef short bf16x4 __attribute__((ext_vector_type(4)));
typedef short bf16x8 __attribute__((ext_vector_type(8)));

__device__ __forceinline__ short f2bf(float f) {
  uint32_t u = __builtin_bit_cast(uint32_t, f);
  u += 0x7fffu + ((u >> 16) & 1u);          // RNE
  return (short)(u >> 16);
}

// ---------------- CSR build ----------------
__global__ void countDeg(const int* __restrict__ ni, const int* __restrict__ ei,
                         int* __restrict__ nd, int* __restrict__ ed) {
  int i = blockIdx.x * 256 + threadIdx.x;
  if (i < NNZ_) {
    atomicAdd(&nd[ni[i]], 1);
    atomicAdd(&ed[ei[i]], 1);
  }
}

__global__ void exscan(const int* __restrict__ deg, int* __restrict__ off, int n) {
  __shared__ int wsum[16];
  __shared__ int carry_s;
  int t = threadIdx.x, lane = t & 63, w = t >> 6;
  if (t == 0) carry_s = 0;
  __syncthreads();
  for (int base = 0; base < n; base += 1024) {
    int v = (base + t < n) ? deg[base + t] : 0;
    int x = v;
    #pragma unroll
    for (int d = 1; d < 64; d <<= 1) { int y = __shfl_up(x, d); if (lane >= d) x += y; }
    if (lane == 63) wsum[w] = x;
    __syncthreads();
    if (t < 16) {
      int y = wsum[t];
      #pragma unroll
      for (int d = 1; d < 16; d <<= 1) { int z = __shfl_up(y, d); if (t >= d) y += z; }
      wsum[t] = y;
    }
    __syncthreads();
    int c = carry_s;
    int incl = x + (w ? wsum[w - 1] : 0);
    if (base + t < n) off[base + t] = c + incl - v;
    int total = wsum[15];
    __syncthreads();
    if (t == 0) carry_s = c + total;
    __syncthreads();
  }
  if (threadIdx.x == 0) off[n] = carry_s;
}

__global__ void fillCSR(const int* __restrict__ ni, const int* __restrict__ ei,
                        const int* __restrict__ noff, const int* __restrict__ eoff,
                        int* __restrict__ ncur, int* __restrict__ ecur,
                        int* __restrict__ node_edge, int* __restrict__ edge_node) {
  int i = blockIdx.x * 256 + threadIdx.x;
  if (i < NNZ_) {
    int n = ni[i], e = ei[i];
    int pe = eoff[e] + atomicAdd(&ecur[e], 1);
    edge_node[pe] = n;
    int pn = noff[n] + atomicAdd(&ncur[n], 1);
    node_edge[pn] = e;
  }
}

__global__ void invdeg(const int* __restrict__ nd, const int* __restrict__ ed,
                       float* __restrict__ Dinv, float* __restrict__ Binv) {
  int i = blockIdx.x * 256 + threadIdx.x;
  if (i < N_NODES) { int d = nd[i]; Dinv[i] = d > 0 ? 1.f / (float)d : 0.f; }
  if (i < N_EDGES) { int d = ed[i]; Binv[i] = d > 0 ? 1.f / (float)d : 0.f; }
}

// W [K][N] fp32 -> WT [N][K] bf16
__global__ void convertWT(const float* __restrict__ Wm, short* __restrict__ WT) {
  __shared__ float tile[64][65];
  int tx = threadIdx.x & 63, ty = threadIdx.x >> 6;  // ty 0..3
  int kb = blockIdx.x * 64, nb = blockIdx.y * 64;
  #pragma unroll
  for (int j = 0; j < 64; j += 4)
    tile[j + ty][tx] = Wm[(size_t)(kb + j + ty) * C_DIM + nb + tx];
  __syncthreads();
  #pragma unroll
  for (int j = 0; j < 64; j += 4)
    WT[(size_t)(nb + j + ty) * C_DIM + kb + tx] = f2bf(tile[tx][j + ty]);
}

// ---------------- phaseA: node->edge gather of src with optional fused BN+ReLU,
//                  scaled by Binv, output bf16 [E_PAD, C] ----------------
template <int BN>
__global__ void phaseA_f(const float* __restrict__ src, const int* __restrict__ eoff,
                         const int* __restrict__ enode, const float* __restrict__ Binv,
                         const float* __restrict__ sc, const float* __restrict__ sh,
                         short* __restrict__ Mbf) {
  int e = blockIdx.x;
  int t = threadIdx.x;
  int c = t * 4;
  if (e >= N_EDGES) {
    bf16x4 z = {0, 0, 0, 0};
    *(bf16x4*)&Mbf[(size_t)e * C_DIM + c] = z;
    return;
  }
  f32x4 scl, shf;
  if (BN) {
    scl = *(const f32x4*)&sc[c];
    shf = *(const f32x4*)&sh[c];
  }
  int beg = eoff[e], end = eoff[e + 1];
  f32x4 acc0 = {0.f, 0.f, 0.f, 0.f}, acc1 = {0.f, 0.f, 0.f, 0.f};
  int i = beg;
  for (; i + 1 < end; i += 2) {
    f32x4 v0 = *(const f32x4*)&src[(size_t)enode[i] * C_DIM + c];
    f32x4 v1 = *(const f32x4*)&src[(size_t)enode[i + 1] * C_DIM + c];
    if (BN) {
      #pragma unroll
      for (int j = 0; j < 4; ++j) {
        v0[j] = fmaxf(v0[j] * scl[j] + shf[j], 0.f);
        v1[j] = fmaxf(v1[j] * scl[j] + shf[j], 0.f);
      }
    }
    acc0 += v0;
    acc1 += v1;
  }
  if (i < end) {
    f32x4 v = *(const f32x4*)&src[(size_t)enode[i] * C_DIM + c];
    if (BN) {
      #pragma unroll
      for (int j = 0; j < 4; ++j) v[j] = fmaxf(v[j] * scl[j] + shf[j], 0.f);
    }
    acc0 += v;
  }
  float bi = Binv[e];
  f32x4 m = (acc0 + acc1) * bi;
  bf16x4 o;
  #pragma unroll
  for (int j = 0; j < 4; ++j) o[j] = f2bf(m[j]);
  *(bf16x4*)&Mbf[(size_t)e * C_DIM + c] = o;
}

// ---------------- GEMM: C[E_PAD,1024] = A[E_PAD,1024]bf16 x BT[1024,1024]bf16 ----------------
__global__ __launch_bounds__(256) void gemm_bf16(const short* __restrict__ A,
                                                 const short* __restrict__ BT,
                                                 float* __restrict__ Cc) {
  __shared__ __align__(16) short As[2][128 * 32];
  __shared__ __align__(16) short Bs[2][128 * 32];
  const int tid = threadIdx.x;
  const int w = tid >> 6;
  const int lane = tid & 63;
  const int bm = blockIdx.x, bn = blockIdx.y;
  const int wr = w >> 1, wc = w & 1;
  const int fr = lane & 15, kg = lane >> 4;
  const int qa = w * 2;
  const int srow = lane >> 2;        // 0..15
  const int skof = (lane & 3) * 8;   // 0,8,16,24

  f32x4 acc[4][4] = {};

  auto stage = [&](int ks, int buf) {
    #pragma unroll
    for (int c2 = 0; c2 < 2; ++c2) {
      int q = qa + c2;
      int row = q * 16 + srow;
      size_t gA = (size_t)(bm * 128 + row) * C_DIM + ks * 32 + skof;
      size_t gB = (size_t)(bn * 128 + row) * C_DIM + ks * 32 + skof;
      __builtin_amdgcn_global_load_lds(
          (__attribute__((address_space(1))) void*)(A + gA),
          (__attribute__((address_space(3))) void*)(&As[buf][q * 512]), 16, 0, 0);
      __builtin_amdgcn_global_load_lds(
          (__attribute__((address_space(1))) void*)(BT + gB),
          (__attribute__((address_space(3))) void*)(&Bs[buf][q * 512]), 16, 0, 0);
    }
  };
  auto compute = [&](int buf) {
    bf16x8 a[4], b[4];
    #pragma unroll
    for (int m = 0; m < 4; ++m)
      a[m] = *(const bf16x8*)&As[buf][(wr * 64 + m * 16 + fr) * 32 + kg * 8];
    #pragma unroll
    for (int n = 0; n < 4; ++n)
      b[n] = *(const bf16x8*)&Bs[buf][(wc * 64 + n * 16 + fr) * 32 + kg * 8];
    #pragma unroll
    for (int m = 0; m < 4; ++m)
      #pragma unroll
      for (int n = 0; n < 4; ++n)
        acc[m][n] = __builtin_amdgcn_mfma_f32_16x16x32_bf16(a[m], b[n], acc[m][n], 0, 0, 0);
  };

  stage(0, 0);
  __syncthreads();
  for (int ks = 0; ks < 31; ++ks) {
    stage(ks + 1, (ks + 1) & 1);
    compute(ks & 1);
    __syncthreads();
  }
  compute(1);

  const int row0 = bm * 128 + wr * 64 + kg * 4;
  const int col0 = bn * 128 + wc * 64 + fr;
  #pragma unroll
  for (int m = 0; m < 4; ++m) {
    #pragma unroll
    for (int n = 0; n < 4; ++n) {
      int r = row0 + m * 16, cc = col0 + n * 16;
      #pragma unroll
      for (int j = 0; j < 4; ++j)
        Cc[(size_t)(r + j) * C_DIM + cc] = acc[m][n][j];
    }
  }
}

// ---------------- phaseB: edge->node gather of Mw (L2-resident), + bias ----------------
__global__ void phaseB(const float* __restrict__ M, const int* __restrict__ noff,
                       const int* __restrict__ nedge, const float* __restrict__ Dinv,
                       const float* __restrict__ bias, float* __restrict__ Out) {
  int n = blockIdx.x;
  int t = threadIdx.x;
  int beg = noff[n], end = noff[n + 1];
  f32x4 acc0 = {0.f, 0.f, 0.f, 0.f}, acc1 = {0.f, 0.f, 0.f, 0.f};
  int i = beg;
  for (; i + 1 < end; i += 2) {
    int e0 = nedge[i], e1 = nedge[i + 1];
    acc0 += *(const f32x4*)&M[(size_t)e0 * C_DIM + t * 4];
    acc1 += *(const f32x4*)&M[(size_t)e1 * C_DIM + t * 4];
  }
  if (i < end) acc0 += *(const f32x4*)&M[(size_t)nedge[i] * C_DIM + t * 4];
  float di = Dinv[n];
  f32x4 b = *(const f32x4*)&bias[t * 4];
  *(f32x4*)&Out[(size_t)n * C_DIM + t * 4] = (acc0 + acc1) * di + b;
}

// ---------------- batch norm: atomic-free two-stage ----------------
__global__ void bnstats_part(const float* __restrict__ H, float* __restrict__ ps,
                             float* __restrict__ pq) {
  int c = threadIdx.x * 4;
  int b = blockIdx.x;
  int r0 = b * 128;
  int r1 = r0 + 128 < N_NODES ? r0 + 128 : N_NODES;
  f32x4 s = {0.f, 0.f, 0.f, 0.f}, q = {0.f, 0.f, 0.f, 0.f};
  for (int r = r0; r < r1; ++r) {
    f32x4 v = *(const f32x4*)&H[(size_t)r * C_DIM + c];
    s += v;
    q += v * v;
  }
  *(f32x4*)&ps[(size_t)b * C_DIM + c] = s;
  *(f32x4*)&pq[(size_t)b * C_DIM + c] = q;
}

__global__ void bnfinal2(const float* __restrict__ ps, const float* __restrict__ pq,
                         const float* __restrict__ g, const float* __restrict__ be,
                         float* __restrict__ scale, float* __restrict__ shift) {
  int c = blockIdx.x * 256 + threadIdx.x;
  float s = 0.f, q = 0.f;
  for (int p = 0; p < NBLK_BN; ++p) {
    s += ps[(size_t)p * C_DIM + c];
    q += pq[(size_t)p * C_DIM + c];
  }
  const float invN = 1.f / (float)N_NODES;
  float mu = s * invN;
  float var = q * invN - mu * mu;
  float rs = rsqrtf(var + BN_EPS);
  float scl = g[c] * rs;
  scale[c] = scl;
  shift[c] = be[c] - mu * scl;
}

// ---------------- final pooling + fc + sigmoid (atomic-light) ----------------
__global__ void finaldot_rows(const float* __restrict__ H, const float* __restrict__ sc,
                              const float* __restrict__ sh, const float* __restrict__ Wfc,
                              float* __restrict__ rows) {
  int row = blockIdx.x * 4 + (threadIdx.x >> 6);
  int lane = threadIdx.x & 63;
  if (row >= N_NODES) return;
  const float* hr = H + (size_t)row * C_DIM;
  float s = 0.f;
  #pragma unroll
  for (int j = 0; j < 4; ++j) {
    int c = j * 256 + lane * 4;
    f32x4 v = *(const f32x4*)&hr[c];
    f32x4 a = *(const f32x4*)&sc[c];
    f32x4 b = *(const f32x4*)&sh[c];
    f32x4 w = *(const f32x4*)&Wfc[c];
    #pragma unroll
    for (int k = 0; k < 4; ++k) s += fmaxf(v[k] * a[k] + b[k], 0.f) * w[k];
  }
  #pragma unroll
  for (int off = 32; off; off >>= 1) s += __shfl_down(s, off);
  if (lane == 0) rows[row] = s;
}

// batch is sorted -> LDS bins then few global atomics
__global__ void poolbin(const float* __restrict__ rows, const int* __restrict__ batch,
                        float* __restrict__ gsum, int* __restrict__ gcnt) {
  __shared__ float bins[N_GRAPHS];
  __shared__ int cbin[N_GRAPHS];
  int t = threadIdx.x;
  if (t < N_GRAPHS) { bins[t] = 0.f; cbin[t] = 0; }
  __syncthreads();
  int quad = blockIdx.x * 256 + t;            // 12500 quads = 50000 rows
  if (quad * 4 < N_NODES) {
    f32x4 r = *(const f32x4*)&rows[quad * 4];
    int4 bi = *(const int4*)&batch[quad * 4];
    int g0 = bi.x;
    float acc = r[0];
    int cc = 1;
    int gn[3] = {bi.y, bi.z, bi.w};
    float rn[3] = {r[1], r[2], r[3]};
    #pragma unroll
    for (int j = 0; j < 3; ++j) {
      if (gn[j] == g0) { acc += rn[j]; ++cc; }
      else {
        atomicAdd(&bins[g0], acc);
        atomicAdd(&cbin[g0], cc);
        g0 = gn[j]; acc = rn[j]; cc = 1;
      }
    }
    atomicAdd(&bins[g0], acc);
    atomicAdd(&cbin[g0], cc);
  }
  __syncthreads();
  if (t < N_GRAPHS && cbin[t] > 0) {
    atomicAdd(&gsum[t], bins[t]);
    atomicAdd(&gcnt[t], cbin[t]);
  }
}

__global__ void finalout(const float* __restrict__ gsum, const int* __restrict__ gcnt,
                         const float* __restrict__ bfc, float* __restrict__ out) {
  int g = threadIdx.x;
  float cnt = (float)(gcnt[g] > 0 ? gcnt[g] : 1);
  float v = gsum[g] / cnt + bfc[0];
  out[g] = 1.f / (1.f + expf(-v));
}

// ---------------- host launcher ----------------
extern "C" void kernel_launch(void* const* d_in, const int* in_sizes, int n_in,
                              void* d_out, int out_size, void* d_ws, size_t ws_size,
                              hipStream_t stream) {
  const float* x        = (const float*)d_in[0];
  const int*   node_idx = (const int*)d_in[1];
  const int*   hedge_idx= (const int*)d_in[2];
  const int*   batch    = (const int*)d_in[3];
  const float* W[3]  = {(const float*)d_in[4], (const float*)d_in[6], (const float*)d_in[8]};
  const float* bb[3] = {(const float*)d_in[5], (const float*)d_in[7], (const float*)d_in[9]};
  const float* g[3]  = {(const float*)d_in[10], (const float*)d_in[12], (const float*)d_in[14]};
  const float* be[3] = {(const float*)d_in[11], (const float*)d_in[13], (const float*)d_in[15]};
  const float* Wfc   = (const float*)d_in[16];
  const float* bfc   = (const float*)d_in[17];
  float* out = (float*)d_out;

  char* ws = (char*)d_ws;
  size_t o = 0;
  auto take = [&](size_t bytes) -> char* {
    char* p = ws + o;
    o += (bytes + 255) & ~(size_t)255;
    return p;
  };
  short* Mbf  = (short*)take((size_t)E_PAD * C_DIM * 2);   // edge features bf16
  short* WT   = (short*)take((size_t)C_DIM * C_DIM * 2);
  float* Mw   = (float*)take((size_t)E_PAD * C_DIM * 4);   // (m*Binv) @ W, fp32
  float* Hbuf = (float*)take((size_t)N_NODES * C_DIM * 4); // conv output (pre-BN)
  char*  zgrp = take(432512);
  int*   node_deg = (int*)zgrp;
  int*   edge_deg = (int*)(zgrp + 200000);
  int*   node_cur = (int*)(zgrp + 216000);
  int*   edge_cur = (int*)(zgrp + 416000);
  float* gsum     = (float*)(zgrp + 432000);
  int*   gcnt     = (int*)(zgrp + 432256);
  int* node_off  = (int*)take((N_NODES + 1) * 4);
  int* edge_off  = (int*)take((N_EDGES + 1) * 4);
  int* node_edge = (int*)take((size_t)NNZ_ * 4);
  int* edge_node = (int*)take((size_t)NNZ_ * 4);
  float* Dinv = (float*)take(N_NODES * 4);
  float* Binv = (float*)take(N_EDGES * 4);
  float* scale = (float*)take(4096);
  float* shift = (float*)take(4096);
  float* part_s = (float*)take((size_t)NBLK_BN * C_DIM * 4);
  float* part_q = (float*)take((size_t)NBLK_BN * C_DIM * 4);
  float* rows   = (float*)take((size_t)N_NODES * 4);

  // zero atomic accumulators (must be re-zeroed every call)
  hipMemsetAsync(zgrp, 0, 432512, stream);

  // degree + CSR build
  countDeg<<<(NNZ_ + 255) / 256, 256, 0, stream>>>(node_idx, hedge_idx, node_deg, edge_deg);
  exscan<<<1, 1024, 0, stream>>>(edge_deg, edge_off, N_EDGES);
  exscan<<<1, 1024, 0, stream>>>(node_deg, node_off, N_NODES);
  fillCSR<<<(NNZ_ + 255) / 256, 256, 0, stream>>>(node_idx, hedge_idx, node_off, edge_off,
                                                  node_cur, edge_cur, node_edge, edge_node);
  invdeg<<<(N_NODES + 255) / 256, 256, 0, stream>>>(node_deg, edge_deg, Dinv, Binv);

  for (int L = 0; L < 3; ++L) {
    if (L == 0)
      phaseA_f<0><<<E_PAD, 256, 0, stream>>>(x, edge_off, edge_node, Binv,
                                             nullptr, nullptr, Mbf);
    else
      phaseA_f<1><<<E_PAD, 256, 0, stream>>>(Hbuf, edge_off, edge_node, Binv,
                                             scale, shift, Mbf);
    convertWT<<<dim3(16, 16), 256, 0, stream>>>(W[L], WT);
    gemm_bf16<<<dim3(E_PAD / 128, C_DIM / 128), 256, 0, stream>>>(Mbf, WT, Mw);
    phaseB<<<N_NODES, 256, 0, stream>>>(Mw, node_off, node_edge, Dinv, bb[L], Hbuf);
    bnstats_part<<<NBLK_BN, 256, 0, stream>>>(Hbuf, part_s, part_q);
    bnfinal2<<<4, 256, 0, stream>>>(part_s, part_q, g[L], be[L], scale, shift);
  }
  finaldot_rows<<<(N_NODES + 3) / 4, 256, 0, stream>>>(Hbuf, scale, shift, Wfc, rows);
  poolbin<<<(N_NODES / 4 + 255) / 256, 256, 0, stream>>>(rows, batch, gsum, gcnt);
  finalout<<<1, 64, 0, stream>>>(gsum, gcnt, bfc, out);
}

// Round 7
// 1435.245 us; speedup vs baseline: 1.9073x; 1.2920x over previous
//
#include <hip/hip_runtime.h>
#include <cstdint>
#include <cstddef>

#define N_NODES  50000
#define N_EDGES  4000
#define E_PAD    4096    // 32*128
#define NNZ_     400000
#define N_GRAPHS 64
#define C_DIM    1024
#define NBLK_BN  391
#define BN_EPS   1e-5f

typedef float f32x4  __attribute__((ext_vector_type(4)));
typedef short bf16x4 __attribute__((ext_vector_type(4)));
typedef short bf16x8 __attribute__((ext_vector_type(8)));

__device__ __forceinline__ short f2bf(float f) {
  uint32_t u = __builtin_bit_cast(uint32_t, f);
  u += 0x7fffu + ((u >> 16) & 1u);          // RNE
  return (short)(u >> 16);
}
__device__ __forceinline__ float bf2f(short s) {
  uint32_t u = ((uint32_t)(uint16_t)s) << 16;
  return __builtin_bit_cast(float, u);
}

// ---------------- CSR build ----------------
__global__ void countDeg(const int* __restrict__ ni, const int* __restrict__ ei,
                         int* __restrict__ nd, int* __restrict__ ed) {
  int i = blockIdx.x * 256 + threadIdx.x;
  if (i < NNZ_) {
    atomicAdd(&nd[ni[i]], 1);
    atomicAdd(&ed[ei[i]], 1);
  }
}

__global__ void exscan(const int* __restrict__ deg, int* __restrict__ off, int n) {
  __shared__ int wsum[16];
  __shared__ int carry_s;
  int t = threadIdx.x, lane = t & 63, w = t >> 6;
  if (t == 0) carry_s = 0;
  __syncthreads();
  for (int base = 0; base < n; base += 1024) {
    int v = (base + t < n) ? deg[base + t] : 0;
    int x = v;
    #pragma unroll
    for (int d = 1; d < 64; d <<= 1) { int y = __shfl_up(x, d); if (lane >= d) x += y; }
    if (lane == 63) wsum[w] = x;
    __syncthreads();
    if (t < 16) {
      int y = wsum[t];
      #pragma unroll
      for (int d = 1; d < 16; d <<= 1) { int z = __shfl_up(y, d); if (t >= d) y += z; }
      wsum[t] = y;
    }
    __syncthreads();
    int c = carry_s;
    int incl = x + (w ? wsum[w - 1] : 0);
    if (base + t < n) off[base + t] = c + incl - v;
    int total = wsum[15];
    __syncthreads();
    if (t == 0) carry_s = c + total;
    __syncthreads();
  }
  if (threadIdx.x == 0) off[n] = carry_s;
}

__global__ void fillCSR(const int* __restrict__ ni, const int* __restrict__ ei,
                        const int* __restrict__ noff, const int* __restrict__ eoff,
                        int* __restrict__ ncur, int* __restrict__ ecur,
                        int* __restrict__ node_edge, int* __restrict__ edge_node) {
  int i = blockIdx.x * 256 + threadIdx.x;
  if (i < NNZ_) {
    int n = ni[i], e = ei[i];
    int pe = eoff[e] + atomicAdd(&ecur[e], 1);
    edge_node[pe] = n;
    int pn = noff[n] + atomicAdd(&ncur[n], 1);
    node_edge[pn] = e;
  }
}

__global__ void invdeg(const int* __restrict__ nd, const int* __restrict__ ed,
                       float* __restrict__ Dinv, float* __restrict__ Binv) {
  int i = blockIdx.x * 256 + threadIdx.x;
  if (i < N_NODES) { int d = nd[i]; Dinv[i] = d > 0 ? 1.f / (float)d : 0.f; }
  if (i < N_EDGES) { int d = ed[i]; Binv[i] = d > 0 ? 1.f / (float)d : 0.f; }
}

// W [K][N] fp32 -> WT [N][K] bf16
__global__ void convertWT(const float* __restrict__ Wm, short* __restrict__ WT) {
  __shared__ float tile[64][65];
  int tx = threadIdx.x & 63, ty = threadIdx.x >> 6;  // ty 0..3
  int kb = blockIdx.x * 64, nb = blockIdx.y * 64;
  #pragma unroll
  for (int j = 0; j < 64; j += 4)
    tile[j + ty][tx] = Wm[(size_t)(kb + j + ty) * C_DIM + nb + tx];
  __syncthreads();
  #pragma unroll
  for (int j = 0; j < 64; j += 4)
    WT[(size_t)(nb + j + ty) * C_DIM + kb + tx] = f2bf(tile[tx][j + ty]);
}

// ---------------- streaming converts: fp32 (opt BN+ReLU) -> bf16 [50000,1024] ----------------
__global__ void convertX(const float* __restrict__ X, short* __restrict__ Hbf) {
  size_t idx = ((size_t)blockIdx.x * 256 + threadIdx.x) * 8;
  float v[8];
  *(f32x4*)&v[0] = *(const f32x4*)&X[idx];
  *(f32x4*)&v[4] = *(const f32x4*)&X[idx + 4];
  bf16x8 ov;
  #pragma unroll
  for (int j = 0; j < 8; ++j) ov[j] = f2bf(v[j]);
  *(bf16x8*)&Hbf[idx] = ov;
}

__global__ void applyBN(const float* __restrict__ H, const float* __restrict__ sc,
                        const float* __restrict__ sh, short* __restrict__ Hbf) {
  size_t idx = ((size_t)blockIdx.x * 256 + threadIdx.x) * 8;
  int c = (int)(idx & 1023);
  float v[8], s[8], h[8];
  *(f32x4*)&v[0] = *(const f32x4*)&H[idx];
  *(f32x4*)&v[4] = *(const f32x4*)&H[idx + 4];
  *(f32x4*)&s[0] = *(const f32x4*)&sc[c];
  *(f32x4*)&s[4] = *(const f32x4*)&sc[c + 4];
  *(f32x4*)&h[0] = *(const f32x4*)&sh[c];
  *(f32x4*)&h[4] = *(const f32x4*)&sh[c + 4];
  bf16x8 ov;
  #pragma unroll
  for (int j = 0; j < 8; ++j) ov[j] = f2bf(fmaxf(v[j] * s[j] + h[j], 0.f));
  *(bf16x8*)&Hbf[idx] = ov;
}

// ---------------- phaseA: node->edge gather from bf16 (L3-resident), out bf16 ----------------
__global__ void phaseA_bf(const short* __restrict__ Hbf, const int* __restrict__ eoff,
                          const int* __restrict__ enode, const float* __restrict__ Binv,
                          short* __restrict__ Mbf) {
  int t = threadIdx.x;
  int e = blockIdx.x * 2 + (t >> 7);
  int c = (t & 127) * 8;
  if (e >= N_EDGES) {
    bf16x8 z = {0, 0, 0, 0, 0, 0, 0, 0};
    *(bf16x8*)&Mbf[(size_t)e * C_DIM + c] = z;
    return;
  }
  int beg = eoff[e], end = eoff[e + 1];
  float a0[8] = {0, 0, 0, 0, 0, 0, 0, 0};
  float a1[8] = {0, 0, 0, 0, 0, 0, 0, 0};
  int i = beg;
  for (; i + 1 < end; i += 2) {
    bf16x8 v0 = *(const bf16x8*)&Hbf[(size_t)enode[i] * C_DIM + c];
    bf16x8 v1 = *(const bf16x8*)&Hbf[(size_t)enode[i + 1] * C_DIM + c];
    #pragma unroll
    for (int j = 0; j < 8; ++j) {
      a0[j] += bf2f(v0[j]);
      a1[j] += bf2f(v1[j]);
    }
  }
  if (i < end) {
    bf16x8 v = *(const bf16x8*)&Hbf[(size_t)enode[i] * C_DIM + c];
    #pragma unroll
    for (int j = 0; j < 8; ++j) a0[j] += bf2f(v[j]);
  }
  float bi = Binv[e];
  bf16x8 ov;
  #pragma unroll
  for (int j = 0; j < 8; ++j) ov[j] = f2bf((a0[j] + a1[j]) * bi);
  *(bf16x8*)&Mbf[(size_t)e * C_DIM + c] = ov;
}

// ---------------- GEMM: C[E_PAD,1024]bf16 = A[E_PAD,1024]bf16 x BT[1024,1024]bf16 ----------------
__global__ __launch_bounds__(256) void gemm_bf16(const short* __restrict__ A,
                                                 const short* __restrict__ BT,
                                                 short* __restrict__ Cc) {
  __shared__ __align__(16) short As[2][128 * 32];
  __shared__ __align__(16) short Bs[2][128 * 32];
  const int tid = threadIdx.x;
  const int w = tid >> 6;
  const int lane = tid & 63;
  const int bm = blockIdx.x, bn = blockIdx.y;
  const int wr = w >> 1, wc = w & 1;
  const int fr = lane & 15, kg = lane >> 4;
  const int qa = w * 2;
  const int srow = lane >> 2;        // 0..15
  const int skof = (lane & 3) * 8;   // 0,8,16,24

  f32x4 acc[4][4] = {};

  auto stage = [&](int ks, int buf) {
    #pragma unroll
    for (int c2 = 0; c2 < 2; ++c2) {
      int q = qa + c2;
      int row = q * 16 + srow;
      size_t gA = (size_t)(bm * 128 + row) * C_DIM + ks * 32 + skof;
      size_t gB = (size_t)(bn * 128 + row) * C_DIM + ks * 32 + skof;
      __builtin_amdgcn_global_load_lds(
          (__attribute__((address_space(1))) void*)(A + gA),
          (__attribute__((address_space(3))) void*)(&As[buf][q * 512]), 16, 0, 0);
      __builtin_amdgcn_global_load_lds(
          (__attribute__((address_space(1))) void*)(BT + gB),
          (__attribute__((address_space(3))) void*)(&Bs[buf][q * 512]), 16, 0, 0);
    }
  };
  auto compute = [&](int buf) {
    bf16x8 a[4], b[4];
    #pragma unroll
    for (int m = 0; m < 4; ++m)
      a[m] = *(const bf16x8*)&As[buf][(wr * 64 + m * 16 + fr) * 32 + kg * 8];
    #pragma unroll
    for (int n = 0; n < 4; ++n)
      b[n] = *(const bf16x8*)&Bs[buf][(wc * 64 + n * 16 + fr) * 32 + kg * 8];
    #pragma unroll
    for (int m = 0; m < 4; ++m)
      #pragma unroll
      for (int n = 0; n < 4; ++n)
        acc[m][n] = __builtin_amdgcn_mfma_f32_16x16x32_bf16(a[m], b[n], acc[m][n], 0, 0, 0);
  };

  stage(0, 0);
  __syncthreads();
  for (int ks = 0; ks < 31; ++ks) {
    stage(ks + 1, (ks + 1) & 1);
    compute(ks & 1);
    __syncthreads();
  }
  compute(1);

  const int row0 = bm * 128 + wr * 64 + kg * 4;
  const int col0 = bn * 128 + wc * 64 + fr;
  #pragma unroll
  for (int m = 0; m < 4; ++m) {
    #pragma unroll
    for (int n = 0; n < 4; ++n) {
      int r = row0 + m * 16, cc = col0 + n * 16;
      #pragma unroll
      for (int j = 0; j < 4; ++j)
        Cc[(size_t)(r + j) * C_DIM + cc] = f2bf(acc[m][n][j]);
    }
  }
}

// ---------------- phaseB: edge->node gather of Mw bf16 (cache-resident), + bias ----------------
__global__ void phaseB_bf(const short* __restrict__ M, const int* __restrict__ noff,
                          const int* __restrict__ nedge, const float* __restrict__ Dinv,
                          const float* __restrict__ bias, float* __restrict__ Out) {
  int n = blockIdx.x;
  int t = threadIdx.x;
  int c = t * 4;
  int beg = noff[n], end = noff[n + 1];
  float a0[4] = {0, 0, 0, 0}, a1[4] = {0, 0, 0, 0};
  int i = beg;
  for (; i + 1 < end; i += 2) {
    bf16x4 v0 = *(const bf16x4*)&M[(size_t)nedge[i] * C_DIM + c];
    bf16x4 v1 = *(const bf16x4*)&M[(size_t)nedge[i + 1] * C_DIM + c];
    #pragma unroll
    for (int j = 0; j < 4; ++j) {
      a0[j] += bf2f(v0[j]);
      a1[j] += bf2f(v1[j]);
    }
  }
  if (i < end) {
    bf16x4 v = *(const bf16x4*)&M[(size_t)nedge[i] * C_DIM + c];
    #pragma unroll
    for (int j = 0; j < 4; ++j) a0[j] += bf2f(v[j]);
  }
  float di = Dinv[n];
  f32x4 b = *(const f32x4*)&bias[c];
  f32x4 o;
  #pragma unroll
  for (int j = 0; j < 4; ++j) o[j] = (a0[j] + a1[j]) * di + b[j];
  *(f32x4*)&Out[(size_t)n * C_DIM + c] = o;
}

// ---------------- batch norm: atomic-free two-stage ----------------
__global__ void bnstats_part(const float* __restrict__ H, float* __restrict__ ps,
                             float* __restrict__ pq) {
  int c = threadIdx.x * 4;
  int b = blockIdx.x;
  int r0 = b * 128;
  int r1 = r0 + 128 < N_NODES ? r0 + 128 : N_NODES;
  f32x4 s = {0.f, 0.f, 0.f, 0.f}, q = {0.f, 0.f, 0.f, 0.f};
  for (int r = r0; r < r1; ++r) {
    f32x4 v = *(const f32x4*)&H[(size_t)r * C_DIM + c];
    s += v;
    q += v * v;
  }
  *(f32x4*)&ps[(size_t)b * C_DIM + c] = s;
  *(f32x4*)&pq[(size_t)b * C_DIM + c] = q;
}

__global__ void bnfinal2(const float* __restrict__ ps, const float* __restrict__ pq,
                         const float* __restrict__ g, const float* __restrict__ be,
                         float* __restrict__ scale, float* __restrict__ shift) {
  int c = blockIdx.x * 256 + threadIdx.x;
  float s = 0.f, q = 0.f;
  for (int p = 0; p < NBLK_BN; ++p) {
    s += ps[(size_t)p * C_DIM + c];
    q += pq[(size_t)p * C_DIM + c];
  }
  const float invN = 1.f / (float)N_NODES;
  float mu = s * invN;
  float var = q * invN - mu * mu;
  float rs = rsqrtf(var + BN_EPS);
  float scl = g[c] * rs;
  scale[c] = scl;
  shift[c] = be[c] - mu * scl;
}

// ---------------- final pooling + fc + sigmoid (atomic-light) ----------------
__global__ void finaldot_rows(const float* __restrict__ H, const float* __restrict__ sc,
                              const float* __restrict__ sh, const float* __restrict__ Wfc,
                              float* __restrict__ rows) {
  int row = blockIdx.x * 4 + (threadIdx.x >> 6);
  int lane = threadIdx.x & 63;
  if (row >= N_NODES) return;
  const float* hr = H + (size_t)row * C_DIM;
  float s = 0.f;
  #pragma unroll
  for (int j = 0; j < 4; ++j) {
    int c = j * 256 + lane * 4;
    f32x4 v = *(const f32x4*)&hr[c];
    f32x4 a = *(const f32x4*)&sc[c];
    f32x4 b = *(const f32x4*)&sh[c];
    f32x4 w = *(const f32x4*)&Wfc[c];
    #pragma unroll
    for (int k = 0; k < 4; ++k) s += fmaxf(v[k] * a[k] + b[k], 0.f) * w[k];
  }
  #pragma unroll
  for (int off = 32; off; off >>= 1) s += __shfl_down(s, off);
  if (lane == 0) rows[row] = s;
}

// batch is sorted -> LDS bins then few global atomics
__global__ void poolbin(const float* __restrict__ rows, const int* __restrict__ batch,
                        float* __restrict__ gsum, int* __restrict__ gcnt) {
  __shared__ float bins[N_GRAPHS];
  __shared__ int cbin[N_GRAPHS];
  int t = threadIdx.x;
  if (t < N_GRAPHS) { bins[t] = 0.f; cbin[t] = 0; }
  __syncthreads();
  int quad = blockIdx.x * 256 + t;            // 12500 quads = 50000 rows
  if (quad * 4 < N_NODES) {
    f32x4 r = *(const f32x4*)&rows[quad * 4];
    int4 bi = *(const int4*)&batch[quad * 4];
    int g0 = bi.x;
    float acc = r[0];
    int cc = 1;
    int gn[3] = {bi.y, bi.z, bi.w};
    float rn[3] = {r[1], r[2], r[3]};
    #pragma unroll
    for (int j = 0; j < 3; ++j) {
      if (gn[j] == g0) { acc += rn[j]; ++cc; }
      else {
        atomicAdd(&bins[g0], acc);
        atomicAdd(&cbin[g0], cc);
        g0 = gn[j]; acc = rn[j]; cc = 1;
      }
    }
    atomicAdd(&bins[g0], acc);
    atomicAdd(&cbin[g0], cc);
  }
  __syncthreads();
  if (t < N_GRAPHS && cbin[t] > 0) {
    atomicAdd(&gsum[t], bins[t]);
    atomicAdd(&gcnt[t], cbin[t]);
  }
}

__global__ void finalout(const float* __restrict__ gsum, const int* __restrict__ gcnt,
                         const float* __restrict__ bfc, float* __restrict__ out) {
  int g = threadIdx.x;
  float cnt = (float)(gcnt[g] > 0 ? gcnt[g] : 1);
  float v = gsum[g] / cnt + bfc[0];
  out[g] = 1.f / (1.f + expf(-v));
}

// ---------------- host launcher ----------------
extern "C" void kernel_launch(void* const* d_in, const int* in_sizes, int n_in,
                              void* d_out, int out_size, void* d_ws, size_t ws_size,
                              hipStream_t stream) {
  const float* x        = (const float*)d_in[0];
  const int*   node_idx = (const int*)d_in[1];
  const int*   hedge_idx= (const int*)d_in[2];
  const int*   batch    = (const int*)d_in[3];
  const float* W[3]  = {(const float*)d_in[4], (const float*)d_in[6], (const float*)d_in[8]};
  const float* bb[3] = {(const float*)d_in[5], (const float*)d_in[7], (const float*)d_in[9]};
  const float* g[3]  = {(const float*)d_in[10], (const float*)d_in[12], (const float*)d_in[14]};
  const float* be[3] = {(const float*)d_in[11], (const float*)d_in[13], (const float*)d_in[15]};
  const float* Wfc   = (const float*)d_in[16];
  const float* bfc   = (const float*)d_in[17];
  float* out = (float*)d_out;

  char* ws = (char*)d_ws;
  size_t o = 0;
  auto take = [&](size_t bytes) -> char* {
    char* p = ws + o;
    o += (bytes + 255) & ~(size_t)255;
    return p;
  };
  short* Hbf  = (short*)take((size_t)N_NODES * C_DIM * 2);  // bf16 gather source (102 MB)
  short* Mbf  = (short*)take((size_t)E_PAD * C_DIM * 2);    // edge features bf16
  short* WT   = (short*)take((size_t)C_DIM * C_DIM * 2);
  short* Mw   = (short*)take((size_t)E_PAD * C_DIM * 2);    // (m*Binv) @ W, bf16
  float* Hbuf = (float*)take((size_t)N_NODES * C_DIM * 4);  // conv output (pre-BN)
  char*  zgrp = take(432512);
  int*   node_deg = (int*)zgrp;
  int*   edge_deg = (int*)(zgrp + 200000);
  int*   node_cur = (int*)(zgrp + 216000);
  int*   edge_cur = (int*)(zgrp + 416000);
  float* gsum     = (float*)(zgrp + 432000);
  int*   gcnt     = (int*)(zgrp + 432256);
  int* node_off  = (int*)take((N_NODES + 1) * 4);
  int* edge_off  = (int*)take((N_EDGES + 1) * 4);
  int* node_edge = (int*)take((size_t)NNZ_ * 4);
  int* edge_node = (int*)take((size_t)NNZ_ * 4);
  float* Dinv = (float*)take(N_NODES * 4);
  float* Binv = (float*)take(N_EDGES * 4);
  float* scale = (float*)take(4096);
  float* shift = (float*)take(4096);
  float* part_s = (float*)take((size_t)NBLK_BN * C_DIM * 4);
  float* part_q = (float*)take((size_t)NBLK_BN * C_DIM * 4);
  float* rows   = (float*)take((size_t)N_NODES * 4);

  // zero atomic accumulators (must be re-zeroed every call)
  hipMemsetAsync(zgrp, 0, 432512, stream);

  // degree + CSR build
  countDeg<<<(NNZ_ + 255) / 256, 256, 0, stream>>>(node_idx, hedge_idx, node_deg, edge_deg);
  exscan<<<1, 1024, 0, stream>>>(edge_deg, edge_off, N_EDGES);
  exscan<<<1, 1024, 0, stream>>>(node_deg, node_off, N_NODES);
  fillCSR<<<(NNZ_ + 255) / 256, 256, 0, stream>>>(node_idx, hedge_idx, node_off, edge_off,
                                                  node_cur, edge_cur, node_edge, edge_node);
  invdeg<<<(N_NODES + 255) / 256, 256, 0, stream>>>(node_deg, edge_deg, Dinv, Binv);

  const int cgrid = (int)((size_t)N_NODES * C_DIM / (8 * 256));  // 25000
  for (int L = 0; L < 3; ++L) {
    if (L == 0)
      convertX<<<cgrid, 256, 0, stream>>>(x, Hbf);
    else
      applyBN<<<cgrid, 256, 0, stream>>>(Hbuf, scale, shift, Hbf);
    phaseA_bf<<<E_PAD / 2, 256, 0, stream>>>(Hbf, edge_off, edge_node, Binv, Mbf);
    convertWT<<<dim3(16, 16), 256, 0, stream>>>(W[L], WT);
    gemm_bf16<<<dim3(E_PAD / 128, C_DIM / 128), 256, 0, stream>>>(Mbf, WT, Mw);
    phaseB_bf<<<N_NODES, 256, 0, stream>>>(Mw, node_off, node_edge, Dinv, bb[L], Hbuf);
    bnstats_part<<<NBLK_BN, 256, 0, stream>>>(Hbuf, part_s, part_q);
    bnfinal2<<<4, 256, 0, stream>>>(part_s, part_q, g[L], be[L], scale, shift);
  }
  finaldot_rows<<<(N_NODES + 3) / 4, 256, 0, stream>>>(Hbuf, scale, shift, Wfc, rows);
  poolbin<<<(N_NODES / 4 + 255) / 256, 256, 0, stream>>>(rows, batch, gsum, gcnt);
  finalout<<<1, 64, 0, stream>>>(gsum, gcnt, bfc, out);
}